// Round 2
// baseline (2483.529 us; speedup 1.0000x reference)
//
#include <hip/hip_runtime.h>

// ---------------------------------------------------------------------------
// ScaledDotProductAttention with mask + deterministic JAX-threefry dropout.
// B=8 H=16 S=1024 D=64, fp32. Outputs: [output | attn_weights] concatenated.
// Round 2: JAX partitionable-threefry dropout (bits[i] = o0^o1 of
//          threefry2x32(key, (hi32(i), lo32(i)))); fp32 compute otherwise.
// ---------------------------------------------------------------------------

constexpr int Bc = 8, Hc = 16, Sc = 1024, Dc = 64;
constexpr int TQ  = 4;    // q-rows per batch per block
constexpr int KC  = 32;   // k-chunk
constexpr int NCH = Sc / KC;  // 32

#define TF_ROUND(x0, x1, r) { x0 += x1; x1 = ((x1 << (r)) | (x1 >> (32 - (r)))); x1 ^= x0; }

// Exact JAX threefry2x32 (20 rounds, 5 key injections).
__host__ __device__ __forceinline__ void threefry2x32(unsigned k0, unsigned k1,
                                                      unsigned x0, unsigned x1,
                                                      unsigned& o0, unsigned& o1) {
  const unsigned k2 = k0 ^ k1 ^ 0x1BD11BDAu;
  x0 += k0; x1 += k1;
  TF_ROUND(x0, x1, 13) TF_ROUND(x0, x1, 15) TF_ROUND(x0, x1, 26) TF_ROUND(x0, x1, 6)
  x0 += k1; x1 += k2 + 1u;
  TF_ROUND(x0, x1, 17) TF_ROUND(x0, x1, 29) TF_ROUND(x0, x1, 16) TF_ROUND(x0, x1, 24)
  x0 += k2; x1 += k0 + 2u;
  TF_ROUND(x0, x1, 13) TF_ROUND(x0, x1, 15) TF_ROUND(x0, x1, 26) TF_ROUND(x0, x1, 6)
  x0 += k0; x1 += k1 + 3u;
  TF_ROUND(x0, x1, 17) TF_ROUND(x0, x1, 29) TF_ROUND(x0, x1, 16) TF_ROUND(x0, x1, 24)
  x0 += k1; x1 += k2 + 4u;
  TF_ROUND(x0, x1, 13) TF_ROUND(x0, x1, 15) TF_ROUND(x0, x1, 26) TF_ROUND(x0, x1, 6)
  x0 += k2; x1 += k0 + 5u;
  o0 = x0; o1 = x1;
}

__global__ __launch_bounds__(256)
void attn_fused(const float* __restrict__ Qg, const float* __restrict__ Kg,
                const float* __restrict__ Vg, const int* __restrict__ Mg,
                float* __restrict__ Og, float* __restrict__ Ag,
                unsigned key0, unsigned key1)
{
  __shared__ __align__(16) float Qs[8][64];       // q rows (pre-scaled by 1/8)
  __shared__ __align__(16) float KV[2 * 64 * 33]; // phase1: K^T chunk; phase3: V chunk
  __shared__ __align__(16) float W[8][1024];      // score / prob rows
  __shared__ __align__(16) float AUX[512];        // phase-3 cross-wave accumulator

  const int tid = threadIdx.x;
  const int b4  = blockIdx.z;          // 0..3 (batch pair: b4 and b4+4)
  const int h   = blockIdx.y;          // 0..15
  const int q0  = blockIdx.x * TQ;

  const int r    = tid >> 5;           // row 0..7 (rows 0-3: batch b4, 4-7: b4+4)
  const int p    = r >> 2;
  const int qi   = r & 3;
  const int lane = tid & 31;
  const int b    = b4 + 4 * p;
  const int q    = q0 + qi;

  // ---- stage Q, scaled by 1/sqrt(64)=0.125 (exact power of 2) ----
  if (tid < 128) {
    const int rr = tid >> 4;
    const int dq = (tid & 15) * 4;
    const int bq = b4 + 4 * (rr >> 2);
    const int qq = q0 + (rr & 3);
    const float4 f = *(const float4*)(Qg + ((size_t)((bq * Hc + h) * Sc + qq) * Dc + dq));
    Qs[rr][dq + 0] = f.x * 0.125f;
    Qs[rr][dq + 1] = f.y * 0.125f;
    Qs[rr][dq + 2] = f.z * 0.125f;
    Qs[rr][dq + 3] = f.w * 0.125f;
  }

  // ---- phase 1: scores = (Q/8) . K  -> W ----
  for (int c = 0; c < NCH; ++c) {
    __syncthreads();   // also orders Qs staging before first compute
    #pragma unroll
    for (int j = 0; j < 4; ++j) {
      const int idx = tid + 256 * j;        // 1024 float4 loads: 2 batches x 32 k x 16 quads
      const int pp  = idx >> 9;
      const int rem = idx & 511;
      const int kk  = rem >> 4;
      const int dq  = (rem & 15) * 4;
      const int bb  = b4 + 4 * pp;
      const float4 f = *(const float4*)(Kg + ((size_t)((bb * Hc + h) * Sc + (c * KC + kk)) * Dc + dq));
      float* dst = &KV[(pp * 64 + dq) * 33 + kk];   // transposed, pad 33 -> conflict-free reads
      dst[0]  = f.x;  dst[33] = f.y;  dst[66] = f.z;  dst[99] = f.w;
    }
    __syncthreads();
    float acc = 0.f;
    const float* qrow = &Qs[r][0];
    const float* kcol = &KV[p * 64 * 33 + lane];
    #pragma unroll
    for (int d = 0; d < 64; ++d)
      acc = fmaf(qrow[d], kcol[d * 33], acc);
    W[r][c * KC + lane] = acc;   // own slot; re-read only by this thread until phase 3 barrier
  }

  // ---- phase 2: mask, softmax, dropout ----
  const int* mrow = Mg + ((size_t)b * Sc + q) * Sc;   // mask is [B,1,S,S], broadcast over h
  const float NEG_INF = -__builtin_inff();
  float sv[NCH];
  float mx = NEG_INF;
  #pragma unroll
  for (int c = 0; c < NCH; ++c) {
    const int k = c * KC + lane;
    float s = W[r][k];
    s = (mrow[k] == 0) ? NEG_INF : s;
    sv[c] = s;
    mx = fmaxf(mx, s);
  }
  #pragma unroll
  for (int off = 16; off > 0; off >>= 1)
    mx = fmaxf(mx, __shfl_xor(mx, off, 32));
  float sum = 0.f;
  #pragma unroll
  for (int c = 0; c < NCH; ++c) {
    const float e = __expf(sv[c] - mx);
    sv[c] = e;
    sum += e;
  }
  #pragma unroll
  for (int off = 16; off > 0; off >>= 1)
    sum += __shfl_xor(sum, off, 32);
  const float inv9 = 1.0f / (sum * 0.9f);   // softmax-normalize and /(1-p) in one multiply

  // dropout bits, JAX threefry_partitionable scheme:
  //   flat index i (< 2^27 here) -> (o0,o1) = threefry2x32(key, (hi32(i)=0, lo32(i)=i))
  //   bits[i] = o0 ^ o1;  u = bitcast((bits>>9)|0x3f800000)-1;  keep = u < 0.9f
  unsigned keep = 0;
  {
    const unsigned base = ((unsigned)((b * Hc + h) * Sc + q)) * (unsigned)Sc + (unsigned)lane;
    #pragma unroll
    for (int c = 0; c < NCH; ++c) {
      unsigned o0, o1;
      threefry2x32(key0, key1, 0u, base + (unsigned)(c * KC), o0, o1);
      const unsigned bits = o0 ^ o1;
      const float u = __uint_as_float((bits >> 9) | 0x3f800000u) - 1.0f;  // [0,1)
      keep |= (u < 0.9f) ? (1u << c) : 0u;
    }
  }

  float* arow = Ag + (((size_t)b * Hc + h) * Sc + q) * Sc;
  #pragma unroll
  for (int c = 0; c < NCH; ++c) {
    const int k = c * KC + lane;
    const float w = ((keep >> c) & 1u) ? sv[c] * inv9 : 0.f;
    W[r][k] = w;
    arow[k] = w;
  }

  // ---- phase 3: output = W . V ----
  __syncthreads();                     // W complete for cross-thread reads
  const int pb  = tid >> 7;            // batch half
  const int kw  = (tid >> 6) & 1;      // k-half of chunk handled by this wave
  const int l64 = tid & 63;
  const int d4  = l64 & 15;            // d quad
  const int ks2 = l64 >> 4;            // k slice (4-way, reduced by shfl)
  float4 acc[4];
  #pragma unroll
  for (int i = 0; i < 4; ++i) acc[i] = make_float4(0.f, 0.f, 0.f, 0.f);

  for (int c = 0; c < NCH; ++c) {
    __syncthreads();
    #pragma unroll
    for (int j = 0; j < 4; ++j) {
      const int idx = tid + 256 * j;
      const int pp  = idx >> 9;
      const int rem = idx & 511;
      const int kk  = rem >> 4;
      const int dq  = (rem & 15) * 4;
      const int bb  = b4 + 4 * pp;
      const float4 f = *(const float4*)(Vg + ((size_t)((bb * Hc + h) * Sc + (c * KC + kk)) * Dc + dq));
      *(float4*)(&KV[(pp * 32 + kk) * 64 + dq]) = f;
    }
    __syncthreads();
    #pragma unroll
    for (int kj = 0; kj < 4; ++kj) {
      const int kk = kw * 16 + ks2 * 4 + kj;
      const float4 v = *(const float4*)(&KV[(pb * 32 + kk) * 64 + d4 * 4]);
      #pragma unroll
      for (int qq = 0; qq < 4; ++qq) {
        const float w = W[pb * 4 + qq][c * KC + kk];
        acc[qq].x = fmaf(w, v.x, acc[qq].x);
        acc[qq].y = fmaf(w, v.y, acc[qq].y);
        acc[qq].z = fmaf(w, v.z, acc[qq].z);
        acc[qq].w = fmaf(w, v.w, acc[qq].w);
      }
    }
  }
  // reduce the 4 ks2 slices (lane bits 4,5 within the wave)
  #pragma unroll
  for (int off = 16; off <= 32; off <<= 1) {
    #pragma unroll
    for (int qq = 0; qq < 4; ++qq) {
      acc[qq].x += __shfl_xor(acc[qq].x, off, 64);
      acc[qq].y += __shfl_xor(acc[qq].y, off, 64);
      acc[qq].z += __shfl_xor(acc[qq].z, off, 64);
      acc[qq].w += __shfl_xor(acc[qq].w, off, 64);
    }
  }
  __syncthreads();   // AUX free; use for cross-wave combine
  float* xacc = AUX; // [pb][qq][d4][4]
  if (kw == 1 && ks2 == 0) {
    #pragma unroll
    for (int qq = 0; qq < 4; ++qq)
      *(float4*)(&xacc[((pb * 4 + qq) * 16 + d4) * 4]) = acc[qq];
  }
  __syncthreads();
  if (kw == 0 && ks2 == 0) {
    #pragma unroll
    for (int qq = 0; qq < 4; ++qq) {
      const float4 o = *(const float4*)(&xacc[((pb * 4 + qq) * 16 + d4) * 4]);
      const int bo = b4 + 4 * pb;
      const int qo = q0 + qq;
      const float4 res = make_float4(acc[qq].x + o.x, acc[qq].y + o.y,
                                     acc[qq].z + o.z, acc[qq].w + o.w);
      *(float4*)(Og + (((size_t)bo * Hc + h) * Sc + qo) * Dc + d4 * 4) = res;
    }
  }
}

extern "C" void kernel_launch(void* const* d_in, const int* in_sizes, int n_in,
                              void* d_out, int out_size, void* d_ws, size_t ws_size,
                              hipStream_t stream) {
  const float* Qg = (const float*)d_in[0];
  const float* Kg = (const float*)d_in[1];
  const float* Vg = (const float*)d_in[2];
  const int*   Mg = (const int*)d_in[3];
  float* Og = (float*)d_out;
  float* Ag = Og + (size_t)Bc * Hc * Sc * Dc;   // attn_weights after output

  // drop_key = fold_in(key(42), 7) = threefry2x32(key=[0,42], counts=[0,7])
  // (fold_in always uses the direct 2-element threefry_2x32 path, flag-independent)
  unsigned k0, k1;
  threefry2x32(0u, 42u, 0u, 7u, k0, k1);

  dim3 grid(Sc / TQ, Hc, Bc / 2);   // (256, 16, 4)
  attn_fused<<<grid, 256, 0, stream>>>(Qg, Kg, Vg, Mg, Og, Ag, k0, k1);
}